// Round 11
// baseline (45.854 us; speedup 1.0000x reference)
//
#include <hip/hip_runtime.h>
#include <math.h>

#define C 64
#define IN_DIM 148
#define ODIM 9      // outputs per edge
#define EPT 2       // edges per thread in edge kernel (4 gathers in flight)
#define BE (256 * EPT)   // edges per block (512); E=1.6M = 3125 * 512 exactly
// proj row = 9 values, 12-bit fixed point, packed in 16B (aligned, 1 line-piece)
// dequant: v = u/256 - 8   (range +-8, step 1/256, max err 1.95e-3)

typedef _Float16 half_t;
typedef float f4 __attribute__((ext_vector_type(4)));
typedef _Float16 h2 __attribute__((ext_vector_type(2)));
typedef unsigned int u32;
typedef u32 u4 __attribute__((ext_vector_type(4)));
typedef int i2 __attribute__((ext_vector_type(2)));

__device__ __forceinline__ float tanh_fast(float x) {
    // tanh(x) = 1 - 2/(e^{2x}+1); saturates correctly at +/-inf
    float e = __expf(2.0f * x);
    return 1.0f - 2.0f / (e + 1.0f);
}

__device__ __forceinline__ void decode9(u4 w, int u[ODIM]) {
    // 12-bit fields at bit offsets 12*i in the 128-bit word
    u[0] = w.x & 0xFFF;
    u[1] = (w.x >> 12) & 0xFFF;
    u[2] = __builtin_amdgcn_alignbit(w.y, w.x, 24) & 0xFFF;
    u[3] = (w.y >> 4) & 0xFFF;
    u[4] = (w.y >> 16) & 0xFFF;
    u[5] = __builtin_amdgcn_alignbit(w.z, w.y, 28) & 0xFFF;
    u[6] = (w.z >> 8) & 0xFFF;
    u[7] = (w.z >> 20) & 0xFFF;
    u[8] = w.w & 0xFFF;
}

// ---------------- node projection kernel: 2 threads per node (src/dst half) --
__global__ __launch_bounds__(256) void node_proj_kernel(
    const float* __restrict__ x, const int* __restrict__ node_types,
    const float* __restrict__ W, u4* __restrict__ sp, u4* __restrict__ dp,
    int N)
{
    __shared__ _Float16 Wh[2 * ODIM][C];   // r<9: W[r][c]; r>=9: W[r-9][64+c]  (fp16)
    __shared__ float ntab[2][ODIM][4];     // [0]=src-type consts, [1]=dst-type consts

    for (int i = threadIdx.x; i < 2 * ODIM * C; i += 256) {
        int r = i >> 6, c = i & 63;
        int o = (r < ODIM) ? r : r - ODIM;
        int col = (r < ODIM) ? c : (C + c);
        Wh[r][c] = (_Float16)W[o * IN_DIM + col];
    }
    for (int i = threadIdx.x; i < 2 * ODIM * 4; i += 256) {
        int t = i & 3;
        int o = (i >> 2) % ODIM;
        int sd = (i >> 2) / ODIM;
        ntab[sd][o][t] = W[o * IN_DIM + 128 + sd * 4 + t];
    }
    __syncthreads();

    int tid = blockIdx.x * 256 + threadIdx.x;
    int n = tid >> 1;
    int h = tid & 1;                     // 0 = src half, 1 = dst half
    if (n >= N) return;

    const f4* xr = (const f4*)(x + (size_t)n * C);
    h2 xh[32];
#pragma unroll
    for (int q = 0; q < 16; ++q) {
        f4 v = xr[q];
        xh[2 * q]     = h2{(_Float16)v.x, (_Float16)v.y};
        xh[2 * q + 1] = h2{(_Float16)v.z, (_Float16)v.w};
    }

    float acc[ODIM];
#pragma unroll
    for (int o = 0; o < ODIM; ++o) acc[o] = 0.0f;

#pragma unroll
    for (int g = 0; g < 8; ++g) {          // 8 halfs (16B) per group
#pragma unroll
        for (int o = 0; o < ODIM; ++o) {
            const h2* wp = (const h2*)&Wh[h * ODIM + o][g * 8];  // ds_read_b128
            acc[o] = __builtin_amdgcn_fdot2(xh[4 * g + 0], wp[0], acc[o], false);
            acc[o] = __builtin_amdgcn_fdot2(xh[4 * g + 1], wp[1], acc[o], false);
            acc[o] = __builtin_amdgcn_fdot2(xh[4 * g + 2], wp[2], acc[o], false);
            acc[o] = __builtin_amdgcn_fdot2(xh[4 * g + 3], wp[3], acc[o], false);
        }
    }

    int t = node_types[n];
    u32 u[ODIM];
#pragma unroll
    for (int o = 0; o < ODIM; ++o) {
        float v = acc[o] + ntab[h][o][t];
        int q = (int)rintf(fmaf(v, 256.0f, 2048.0f));   // (v+8)*256
        q = q < 0 ? 0 : (q > 4095 ? 4095 : q);
        u[o] = (u32)q;
    }
    u4 w;
    w.x = u[0] | (u[1] << 12) | (u[2] << 24);
    w.y = (u[2] >> 8) | (u[3] << 4) | (u[4] << 16) | (u[5] << 28);
    w.z = (u[5] >> 4) | (u[6] << 8) | (u[7] << 20);
    w.w = u[8];

    (h ? dp : sp)[n] = w;                // one 16B aligned store
}

// ---- edge kernel: EPT=2 (4 gathers in flight), LDS staging, dense NT stores --
__global__ __launch_bounds__(256) void edge_kernel(
    const int* __restrict__ ei, const int* __restrict__ etypes,
    const u4* __restrict__ sp, const u4* __restrict__ dp,
    const float* __restrict__ W, float* __restrict__ out,
    int E)
{
    __shared__ float etab2[12][ODIM];    // etab2[t][o] = W[o][136+t] - 16 (folds dequant offsets)
    __shared__ alignas(16) float sm[BE * ODIM];   // 18432 B staging

    for (int i = threadIdx.x; i < 12 * ODIM; i += 256) {
        int t = i / ODIM, o = i - t * ODIM;
        etab2[t][o] = W[o * IN_DIM + 136 + t] - 16.0f;
    }
    __syncthreads();

    int base = blockIdx.x * BE;
    int e0 = base + threadIdx.x * EPT;

    i2 s2, d2, t2;
    if (e0 + EPT <= E) {
        // streaming, nt: don't evict the L2-resident proj set
        s2 = __builtin_nontemporal_load((const i2*)(ei + e0));
        d2 = __builtin_nontemporal_load((const i2*)(ei + (size_t)E + e0));
        t2 = __builtin_nontemporal_load((const i2*)(etypes + e0));
    } else {
#pragma unroll
        for (int k = 0; k < EPT; ++k) {
            int e = e0 + k; if (e > E - 1) e = E - 1;
            s2[k] = ei[e]; d2[k] = ei[(size_t)E + e]; t2[k] = etypes[e];
        }
    }

    // 4 independent 16B gathers, all issued before first use
    u4 sw[EPT], dw[EPT];
#pragma unroll
    for (int k = 0; k < EPT; ++k) sw[k] = sp[s2[k]];
#pragma unroll
    for (int k = 0; k < EPT; ++k) dw[k] = dp[d2[k]];

#pragma unroll
    for (int k = 0; k < EPT; ++k) {
        int us[ODIM], ud[ODIM];
        decode9(sw[k], us);
        decode9(dw[k], ud);
        const float* eb = &etab2[t2[k]][0];
        float* smrow = &sm[(threadIdx.x * EPT + k) * ODIM];
#pragma unroll
        for (int o = 0; o < ODIM; ++o) {
            float v = fmaf((float)(us[o] + ud[o]), 1.0f / 256.0f, eb[o]);
            smrow[o] = tanh_fast(v);
        }
    }
    __syncthreads();

    // fully line-dense output: contiguous lane-ordered f4 nt stores = whole
    // 64B lines -> streams to HBM, zero L2 pollution, zero partial-line RFO.
    float* ob = out + (size_t)base * ODIM;
    int cnt = E - base; if (cnt > BE) cnt = BE;
    if (cnt == BE) {
        const f4* smv = (const f4*)sm;
        f4* obv = (f4*)ob;
#pragma unroll
        for (int j = threadIdx.x; j < BE * ODIM / 4; j += 256)
            __builtin_nontemporal_store(smv[j], obv + j);
    } else {
        int tot = cnt * ODIM;
        for (int j = threadIdx.x; j < tot; j += 256)
            __builtin_nontemporal_store(sm[j], ob + j);
    }
}

extern "C" void kernel_launch(void* const* d_in, const int* in_sizes, int n_in,
                              void* d_out, int out_size, void* d_ws, size_t ws_size,
                              hipStream_t stream) {
    const float* x      = (const float*)d_in[0];
    const int*   ei     = (const int*)d_in[1];
    const int*   etypes = (const int*)d_in[2];
    const int*   ntypes = (const int*)d_in[3];
    const float* W      = (const float*)d_in[4];
    float* out = (float*)d_out;

    int N = in_sizes[0] / C;    // 100000
    int E = in_sizes[2];        // 1600000

    u4* sp = (u4*)d_ws;                  // N x 16B
    u4* dp = sp + N;                     // N x 16B  (total 3.2 MB)

    int nthreads = N * 2;
    int nblocks  = (nthreads + 255) / 256;
    node_proj_kernel<<<nblocks, 256, 0, stream>>>(x, ntypes, W, sp, dp, N);

    int eblocks = (E + BE - 1) / BE;
    edge_kernel<<<eblocks, 256, 0, stream>>>(ei, etypes, sp, dp, W, out, E);
}

// Round 12
// 45.302 us; speedup vs baseline: 1.0122x; 1.0122x over previous
//
#include <hip/hip_runtime.h>
#include <math.h>

#define C 64
#define IN_DIM 148
#define ODIM 9        // outputs per edge
#define QEDGES 4      // edges processed per 4-lane quad
#define BE 256        // edges per block (= blockDim); E = 1.6M = 6250 * 256 exactly
// proj row = 9 values, 12-bit fixed point, packed in 16B (aligned, 1 line)
// dequant: v = u/256 - 8   (range +-8, step 1/256, max err 1.95e-3)

typedef _Float16 half_t;
typedef float f4 __attribute__((ext_vector_type(4)));
typedef _Float16 h2 __attribute__((ext_vector_type(2)));
typedef unsigned int u32;
typedef unsigned long long u64;
typedef u32 u4 __attribute__((ext_vector_type(4)));
typedef int i4 __attribute__((ext_vector_type(4)));

__device__ __forceinline__ float tanh_fast(float x) {
    // tanh(x) = 1 - 2/(e^{2x}+1); saturates correctly at +/-inf
    float e = __expf(2.0f * x);
    return 1.0f - 2.0f / (e + 1.0f);
}

// quad-local down-shift by 1: lane sub gets lane sub+1's value (DPP, pure VALU)
__device__ __forceinline__ u32 quad_down1(u32 v) {
    // quad_perm [1,2,3,3]: ctrl = 1 | 2<<2 | 3<<4 | 3<<6 = 0xF9
    return (u32)__builtin_amdgcn_mov_dpp((int)v, 0xF9, 0xF, 0xF, true);
}

// ---------------- node projection kernel: 2 threads per node (src/dst half) --
__global__ __launch_bounds__(256) void node_proj_kernel(
    const float* __restrict__ x, const int* __restrict__ node_types,
    const float* __restrict__ W, u4* __restrict__ sp, u4* __restrict__ dp,
    int N)
{
    __shared__ _Float16 Wh[2 * ODIM][C];   // r<9: W[r][c]; r>=9: W[r-9][64+c]  (fp16)
    __shared__ float ntab[2][ODIM][4];     // [0]=src-type consts, [1]=dst-type consts

    for (int i = threadIdx.x; i < 2 * ODIM * C; i += 256) {
        int r = i >> 6, c = i & 63;
        int o = (r < ODIM) ? r : r - ODIM;
        int col = (r < ODIM) ? c : (C + c);
        Wh[r][c] = (_Float16)W[o * IN_DIM + col];
    }
    for (int i = threadIdx.x; i < 2 * ODIM * 4; i += 256) {
        int t = i & 3;
        int o = (i >> 2) % ODIM;
        int sd = (i >> 2) / ODIM;
        ntab[sd][o][t] = W[o * IN_DIM + 128 + sd * 4 + t];
    }
    __syncthreads();

    int tid = blockIdx.x * 256 + threadIdx.x;
    int n = tid >> 1;
    int h = tid & 1;                     // 0 = src half, 1 = dst half
    if (n >= N) return;

    const f4* xr = (const f4*)(x + (size_t)n * C);
    h2 xh[32];
#pragma unroll
    for (int q = 0; q < 16; ++q) {
        f4 v = xr[q];
        xh[2 * q]     = h2{(_Float16)v.x, (_Float16)v.y};
        xh[2 * q + 1] = h2{(_Float16)v.z, (_Float16)v.w};
    }

    float acc[ODIM];
#pragma unroll
    for (int o = 0; o < ODIM; ++o) acc[o] = 0.0f;

#pragma unroll
    for (int g = 0; g < 8; ++g) {          // 8 halfs (16B) per group
#pragma unroll
        for (int o = 0; o < ODIM; ++o) {
            const h2* wp = (const h2*)&Wh[h * ODIM + o][g * 8];  // ds_read_b128
            acc[o] = __builtin_amdgcn_fdot2(xh[4 * g + 0], wp[0], acc[o], false);
            acc[o] = __builtin_amdgcn_fdot2(xh[4 * g + 1], wp[1], acc[o], false);
            acc[o] = __builtin_amdgcn_fdot2(xh[4 * g + 2], wp[2], acc[o], false);
            acc[o] = __builtin_amdgcn_fdot2(xh[4 * g + 3], wp[3], acc[o], false);
        }
    }

    int t = node_types[n];
    u32 u[ODIM];
#pragma unroll
    for (int o = 0; o < ODIM; ++o) {
        float v = acc[o] + ntab[h][o][t];
        int q = (int)rintf(fmaf(v, 256.0f, 2048.0f));   // (v+8)*256
        q = q < 0 ? 0 : (q > 4095 ? 4095 : q);
        u[o] = (u32)q;
    }
    u4 w;
    w.x = u[0] | (u[1] << 12) | (u[2] << 24);
    w.y = (u[2] >> 8) | (u[3] << 4) | (u[4] << 16) | (u[5] << 28);
    w.z = (u[5] >> 4) | (u[6] << 8) | (u[7] << 20);
    w.w = u[8];

    (h ? dp : sp)[n] = w;                // one 16B aligned store
}

// ---- edge kernel: 4 lanes per edge (quad-coalesced dword gathers),
// ---- 4 edges per quad, LDS staging, dense NT output stores ------------------
__global__ __launch_bounds__(256) void edge_kernel(
    const int* __restrict__ ei, const int* __restrict__ etypes,
    const u32* __restrict__ sp, const u32* __restrict__ dp,
    const float* __restrict__ W, float* __restrict__ out,
    int E)
{
    __shared__ float etab2[12][ODIM];    // etab2[t][o] = W[o][136+t] - 16 (folds dequant offsets)
    __shared__ alignas(16) float sm[BE * ODIM];   // 9216 B staging

    for (int i = threadIdx.x; i < 12 * ODIM; i += 256) {
        int t = i / ODIM, o = i - t * ODIM;
        etab2[t][o] = W[o * IN_DIM + 136 + t] - 16.0f;
    }
    __syncthreads();

    int base = blockIdx.x * BE;
    int quad = threadIdx.x >> 2;
    int sub  = threadIdx.x & 3;
    int e0 = base + quad * QEDGES;       // quad owns edges e0..e0+3

    i4 s4, d4, t4;
    if (e0 + QEDGES <= E) {
        // all 4 lanes of the quad load the same 16B (merged); nt: streaming
        s4 = __builtin_nontemporal_load((const i4*)(ei + e0));
        d4 = __builtin_nontemporal_load((const i4*)(ei + (size_t)E + e0));
        t4 = __builtin_nontemporal_load((const i4*)(etypes + e0));
    } else {
#pragma unroll
        for (int k = 0; k < QEDGES; ++k) {
            int e = e0 + k; if (e > E - 1) e = E - 1;
            s4[k] = ei[e]; d4[k] = ei[(size_t)E + e]; t4[k] = etypes[e];
        }
    }

    // 8 independent dword gathers; quad's 4 lanes hit consecutive dwords of
    // the same 16B row -> ONE L1 transaction per row instead of four.
    u32 ws[QEDGES], wd[QEDGES];
#pragma unroll
    for (int k = 0; k < QEDGES; ++k) ws[k] = sp[(size_t)s4[k] * 4 + sub];
#pragma unroll
    for (int k = 0; k < QEDGES; ++k) wd[k] = dp[(size_t)d4[k] * 4 + sub];

    // field o = 3*sub + j sits at local bit offset 4*sub + 12*j of (next:me)
    int off0 = sub * 4;
#pragma unroll
    for (int k = 0; k < QEDGES; ++k) {
        u32 nbs = quad_down1(ws[k]);
        u32 nbd = quad_down1(wd[k]);
        u64 WS = ((u64)nbs << 32) | ws[k];
        u64 WD = ((u64)nbd << 32) | wd[k];
        int el = quad * QEDGES + k;
        const float* eb = &etab2[t4[k]][0];
#pragma unroll
        for (int j = 0; j < 3; ++j) {
            int o = 3 * sub + j;                 // lane3: o in 9..11 -> dropped
            int oc = o < ODIM ? o : ODIM - 1;
            u32 us = (u32)(WS >> (off0 + 12 * j)) & 0xFFF;
            u32 ud = (u32)(WD >> (off0 + 12 * j)) & 0xFFF;
            float v = fmaf((float)(us + ud), 1.0f / 256.0f, eb[oc]);
            float r = tanh_fast(v);
            if (o < ODIM) sm[el * ODIM + o] = r;
        }
    }
    __syncthreads();

    // fully line-dense output: contiguous lane-ordered f4 nt stores = whole
    // 64B lines -> streams to HBM, zero L2 pollution, zero partial-line RFO.
    float* ob = out + (size_t)base * ODIM;
    int cnt = E - base; if (cnt > BE) cnt = BE;
    if (cnt == BE) {
        const f4* smv = (const f4*)sm;
        f4* obv = (f4*)ob;
#pragma unroll
        for (int j = threadIdx.x; j < BE * ODIM / 4; j += 256)
            __builtin_nontemporal_store(smv[j], obv + j);
    } else {
        int tot = cnt * ODIM;
        for (int j = threadIdx.x; j < tot; j += 256)
            __builtin_nontemporal_store(sm[j], ob + j);
    }
}

extern "C" void kernel_launch(void* const* d_in, const int* in_sizes, int n_in,
                              void* d_out, int out_size, void* d_ws, size_t ws_size,
                              hipStream_t stream) {
    const float* x      = (const float*)d_in[0];
    const int*   ei     = (const int*)d_in[1];
    const int*   etypes = (const int*)d_in[2];
    const int*   ntypes = (const int*)d_in[3];
    const float* W      = (const float*)d_in[4];
    float* out = (float*)d_out;

    int N = in_sizes[0] / C;    // 100000
    int E = in_sizes[2];        // 1600000

    u4* sp = (u4*)d_ws;                  // N x 16B
    u4* dp = sp + N;                     // N x 16B  (total 3.2 MB)

    int nthreads = N * 2;
    int nblocks  = (nthreads + 255) / 256;
    node_proj_kernel<<<nblocks, 256, 0, stream>>>(x, ntypes, W, sp, dp, N);

    int eblocks = (E + BE - 1) / BE;
    edge_kernel<<<eblocks, 256, 0, stream>>>(ei, etypes, (const u32*)sp, (const u32*)dp,
                                             W, out, E);
}

// Round 13
// 42.569 us; speedup vs baseline: 1.0772x; 1.0642x over previous
//
#include <hip/hip_runtime.h>
#include <math.h>

#define C 64
#define IN_DIM 148
#define ODIM 9      // outputs per edge
// proj row = 9 values, 12-bit fixed point, packed in 16B (aligned, 1 line-piece)
// dequant: v = u/256 - 8   (range +-8, step 1/256, max err 1.95e-3)

typedef _Float16 half_t;
typedef float f4 __attribute__((ext_vector_type(4)));
typedef _Float16 h2 __attribute__((ext_vector_type(2)));
typedef unsigned int u32;
typedef u32 u4 __attribute__((ext_vector_type(4)));

__device__ __forceinline__ float tanh_fast(float x) {
    // tanh(x) = 1 - 2/(e^{2x}+1); saturates correctly at +/-inf
    float e = __expf(2.0f * x);
    return 1.0f - 2.0f / (e + 1.0f);
}

__device__ __forceinline__ void decode9(u4 w, int u[ODIM]) {
    // 12-bit fields at bit offsets 12*i in the 128-bit word
    u[0] = w.x & 0xFFF;
    u[1] = (w.x >> 12) & 0xFFF;
    u[2] = __builtin_amdgcn_alignbit(w.y, w.x, 24) & 0xFFF;
    u[3] = (w.y >> 4) & 0xFFF;
    u[4] = (w.y >> 16) & 0xFFF;
    u[5] = __builtin_amdgcn_alignbit(w.z, w.y, 28) & 0xFFF;
    u[6] = (w.z >> 8) & 0xFFF;
    u[7] = (w.z >> 20) & 0xFFF;
    u[8] = w.w & 0xFFF;
}

// Two 16B gathers with sc0 (L1-bypass, serve from L2 straight to VGPRs).
// Both issued before the single vmcnt wait -> 2 in flight, zero L1 fill work.
__device__ __forceinline__ void gather2_sc0(const u4* a, const u4* b,
                                            u4& ra, u4& rb) {
    asm volatile(
        "global_load_dwordx4 %0, %2, off sc0\n\t"
        "global_load_dwordx4 %1, %3, off sc0\n\t"
        "s_waitcnt vmcnt(0)"
        : "=&v"(ra), "=&v"(rb)
        : "v"(a), "v"(b));
}

// ---------------- node projection kernel: 2 threads per node (src/dst half) --
__global__ __launch_bounds__(256) void node_proj_kernel(
    const float* __restrict__ x, const int* __restrict__ node_types,
    const float* __restrict__ W, u4* __restrict__ sp, u4* __restrict__ dp,
    int N)
{
    __shared__ _Float16 Wh[2 * ODIM][C];   // r<9: W[r][c]; r>=9: W[r-9][64+c]  (fp16)
    __shared__ float ntab[2][ODIM][4];     // [0]=src-type consts, [1]=dst-type consts

    for (int i = threadIdx.x; i < 2 * ODIM * C; i += 256) {
        int r = i >> 6, c = i & 63;
        int o = (r < ODIM) ? r : r - ODIM;
        int col = (r < ODIM) ? c : (C + c);
        Wh[r][c] = (_Float16)W[o * IN_DIM + col];
    }
    for (int i = threadIdx.x; i < 2 * ODIM * 4; i += 256) {
        int t = i & 3;
        int o = (i >> 2) % ODIM;
        int sd = (i >> 2) / ODIM;
        ntab[sd][o][t] = W[o * IN_DIM + 128 + sd * 4 + t];
    }
    __syncthreads();

    int tid = blockIdx.x * 256 + threadIdx.x;
    int n = tid >> 1;
    int h = tid & 1;                     // 0 = src half, 1 = dst half
    if (n >= N) return;

    const f4* xr = (const f4*)(x + (size_t)n * C);
    h2 xh[32];
#pragma unroll
    for (int q = 0; q < 16; ++q) {
        f4 v = xr[q];
        xh[2 * q]     = h2{(_Float16)v.x, (_Float16)v.y};
        xh[2 * q + 1] = h2{(_Float16)v.z, (_Float16)v.w};
    }

    float acc[ODIM];
#pragma unroll
    for (int o = 0; o < ODIM; ++o) acc[o] = 0.0f;

#pragma unroll
    for (int g = 0; g < 8; ++g) {          // 8 halfs (16B) per group
#pragma unroll
        for (int o = 0; o < ODIM; ++o) {
            const h2* wp = (const h2*)&Wh[h * ODIM + o][g * 8];  // ds_read_b128
            acc[o] = __builtin_amdgcn_fdot2(xh[4 * g + 0], wp[0], acc[o], false);
            acc[o] = __builtin_amdgcn_fdot2(xh[4 * g + 1], wp[1], acc[o], false);
            acc[o] = __builtin_amdgcn_fdot2(xh[4 * g + 2], wp[2], acc[o], false);
            acc[o] = __builtin_amdgcn_fdot2(xh[4 * g + 3], wp[3], acc[o], false);
        }
    }

    int t = node_types[n];
    u32 u[ODIM];
#pragma unroll
    for (int o = 0; o < ODIM; ++o) {
        float v = acc[o] + ntab[h][o][t];
        int q = (int)rintf(fmaf(v, 256.0f, 2048.0f));   // (v+8)*256
        q = q < 0 ? 0 : (q > 4095 ? 4095 : q);
        u[o] = (u32)q;
    }
    u4 w;
    w.x = u[0] | (u[1] << 12) | (u[2] << 24);
    w.y = (u[2] >> 8) | (u[3] << 4) | (u[4] << 16) | (u[5] << 28);
    w.z = (u[5] >> 4) | (u[6] << 8) | (u[7] << 20);
    w.w = u[8];

    (h ? dp : sp)[n] = w;                // one 16B aligned store
}

// ---- edge kernel: 1 edge/thread, sc0 gathers, LDS-staged dense NT stores ----
__global__ __launch_bounds__(256) void edge_kernel(
    const int* __restrict__ ei, const int* __restrict__ etypes,
    const u4* __restrict__ sp, const u4* __restrict__ dp,
    const float* __restrict__ W, float* __restrict__ out,
    int E)
{
    __shared__ float etab2[12][ODIM];    // etab2[t][o] = W[o][136+t] - 16 (folds dequant offsets)
    __shared__ alignas(16) float sm[256 * ODIM];   // 9216 B staging

    for (int i = threadIdx.x; i < 12 * ODIM; i += 256) {
        int t = i / ODIM, o = i - t * ODIM;
        etab2[t][o] = W[o * IN_DIM + 136 + t] - 16.0f;
    }
    __syncthreads();

    int base = blockIdx.x * 256;
    int e = base + threadIdx.x;
    int cnt = E - base; if (cnt > 256) cnt = 256;

    if (threadIdx.x < cnt) {
        // streaming index loads: non-temporal, don't evict the L2-resident proj set
        int s  = __builtin_nontemporal_load(ei + e);
        int d  = __builtin_nontemporal_load(ei + (size_t)E + e);
        int et = __builtin_nontemporal_load(etypes + e);

        // 2 random 16B gathers, L1-bypassed (sc0): no L1 MSHR/fill serialization
        u4 sw, dw;
        gather2_sc0(sp + s, dp + d, sw, dw);

        int us[ODIM], ud[ODIM];
        decode9(sw, us);
        decode9(dw, ud);

        const float* eb = &etab2[et][0];
#pragma unroll
        for (int o = 0; o < ODIM; ++o) {
            float v = fmaf((float)(us[o] + ud[o]), 1.0f / 256.0f, eb[o]);
            sm[threadIdx.x * ODIM + o] = tanh_fast(v);
        }
    }
    __syncthreads();

    // fully line-dense output: each nt store instruction = 64 lanes x 16B
    // contiguous = 16 whole 64B lines -> streams to HBM, zero L2 pollution,
    // zero partial-line RFO (R6/R9 lesson).
    float* ob = out + (size_t)base * ODIM;   // 9216B-aligned
    if (cnt == 256) {
        const f4* smv = (const f4*)sm;
        f4* obv = (f4*)ob;
#pragma unroll
        for (int j = threadIdx.x; j < 256 * ODIM / 4; j += 256)
            __builtin_nontemporal_store(smv[j], obv + j);
    } else {
        int tot = cnt * ODIM;
        for (int j = threadIdx.x; j < tot; j += 256)
            __builtin_nontemporal_store(sm[j], ob + j);
    }
}

extern "C" void kernel_launch(void* const* d_in, const int* in_sizes, int n_in,
                              void* d_out, int out_size, void* d_ws, size_t ws_size,
                              hipStream_t stream) {
    const float* x      = (const float*)d_in[0];
    const int*   ei     = (const int*)d_in[1];
    const int*   etypes = (const int*)d_in[2];
    const int*   ntypes = (const int*)d_in[3];
    const float* W      = (const float*)d_in[4];
    float* out = (float*)d_out;

    int N = in_sizes[0] / C;    // 100000
    int E = in_sizes[2];        // 1600000

    u4* sp = (u4*)d_ws;                  // N x 16B
    u4* dp = sp + N;                     // N x 16B  (total 3.2 MB)

    int nthreads = N * 2;
    int nblocks  = (nthreads + 255) / 256;
    node_proj_kernel<<<nblocks, 256, 0, stream>>>(x, ntypes, W, sp, dp, N);

    int eblocks = (E + 255) / 256;
    edge_kernel<<<eblocks, 256, 0, stream>>>(ei, etypes, sp, dp, W, out, E);
}

// Round 14
// 42.421 us; speedup vs baseline: 1.0809x; 1.0035x over previous
//
#include <hip/hip_runtime.h>
#include <math.h>

#define C 64
#define IN_DIM 148
#define ODIM 9      // outputs per edge
// proj row = 9 values, 12-bit fixed point, packed in 16B (aligned, 1 line-piece)
// dequant: v = u/256 - 8   (range +-8, step 1/256, max err 1.95e-3)

typedef _Float16 half_t;
typedef float f4 __attribute__((ext_vector_type(4)));
typedef _Float16 h2 __attribute__((ext_vector_type(2)));
typedef unsigned int u32;
typedef u32 u4 __attribute__((ext_vector_type(4)));

__device__ __forceinline__ float tanh_fast(float x) {
    // tanh(x) = 1 - 2/(e^{2x}+1); saturates correctly at +/-inf
    float e = __expf(2.0f * x);
    return 1.0f - 2.0f / (e + 1.0f);
}

__device__ __forceinline__ void decode9(u4 w, int u[ODIM]) {
    // 12-bit fields at bit offsets 12*i in the 128-bit word
    u[0] = w.x & 0xFFF;
    u[1] = (w.x >> 12) & 0xFFF;
    u[2] = __builtin_amdgcn_alignbit(w.y, w.x, 24) & 0xFFF;
    u[3] = (w.y >> 4) & 0xFFF;
    u[4] = (w.y >> 16) & 0xFFF;
    u[5] = __builtin_amdgcn_alignbit(w.z, w.y, 28) & 0xFFF;
    u[6] = (w.z >> 8) & 0xFFF;
    u[7] = (w.z >> 20) & 0xFFF;
    u[8] = w.w & 0xFFF;
}

// Two 16B gathers with sc0 (L1-bypass, served from L2 straight to VGPRs).
__device__ __forceinline__ void gather2_sc0(const u4* a, const u4* b,
                                            u4& ra, u4& rb) {
    asm volatile(
        "global_load_dwordx4 %0, %2, off sc0\n\t"
        "global_load_dwordx4 %1, %3, off sc0\n\t"
        "s_waitcnt vmcnt(0)"
        : "=&v"(ra), "=&v"(rb)
        : "v"(a), "v"(b));
}

// 64B contiguous load with sc0 (L1-bypass): 4 dwordx4 off one address + imm
// offsets, single vmcnt. Dodges the per-CU L1 MSHR cap on the x stream.
__device__ __forceinline__ void load4x16_sc0(const float* p, u4& a0, u4& a1,
                                             u4& a2, u4& a3) {
    asm volatile(
        "global_load_dwordx4 %0, %4, off sc0\n\t"
        "global_load_dwordx4 %1, %4, off offset:16 sc0\n\t"
        "global_load_dwordx4 %2, %4, off offset:32 sc0\n\t"
        "global_load_dwordx4 %3, %4, off offset:48 sc0\n\t"
        "s_waitcnt vmcnt(0)"
        : "=&v"(a0), "=&v"(a1), "=&v"(a2), "=&v"(a3)
        : "v"(p));
}

// ------- node projection kernel: 4 threads per node --------------------------
// lane q = (tid&3): h = q&1 (src/dst half), ch = q>>1 (channel half).
// Each lane loads a DISTINCT 64B chunk (no duplicate lines), halves are
// exchanged via shfl_xor(1); partial dots combined via shfl_xor(2).
__global__ __launch_bounds__(256) void node_proj_kernel(
    const float* __restrict__ x, const int* __restrict__ node_types,
    const float* __restrict__ W, u4* __restrict__ sp, u4* __restrict__ dp,
    int N)
{
    __shared__ _Float16 Wh[2 * ODIM][C];   // r<9: W[r][c]; r>=9: W[r-9][64+c]  (fp16)
    __shared__ float ntab[2][ODIM][4];     // [0]=src-type consts, [1]=dst-type consts

    for (int i = threadIdx.x; i < 2 * ODIM * C; i += 256) {
        int r = i >> 6, c = i & 63;
        int o = (r < ODIM) ? r : r - ODIM;
        int col = (r < ODIM) ? c : (C + c);
        Wh[r][c] = (_Float16)W[o * IN_DIM + col];
    }
    for (int i = threadIdx.x; i < 2 * ODIM * 4; i += 256) {
        int t = i & 3;
        int o = (i >> 2) % ODIM;
        int sd = (i >> 2) / ODIM;
        ntab[sd][o][t] = W[o * IN_DIM + 128 + sd * 4 + t];
    }
    __syncthreads();

    int tid = blockIdx.x * 256 + threadIdx.x;
    int n  = tid >> 2;
    int q  = tid & 3;
    int h  = q & 1;                      // 0 = src half, 1 = dst half
    int ch = q >> 1;                     // channel half (0: c<32, 1: c>=32)
    if (n >= N) return;                  // whole quads drop together (shfl-safe)

    // distinct 64B per lane, L1-bypassed
    const float* xp = x + (size_t)n * C + q * 16;
    u4 xc[4];
    load4x16_sc0(xp, xc[0], xc[1], xc[2], xc[3]);

    // partner chunk (xor lane bit 0)
    u4 xn[4];
#pragma unroll
    for (int i = 0; i < 4; ++i)
#pragma unroll
        for (int j = 0; j < 4; ++j)
            xn[i][j] = (u32)__shfl_xor((int)xc[i][j], 1);

    // assemble this lane's 32-channel half (floats ch*32 .. ch*32+31) as fp16 pairs
    h2 xh[16];
#pragma unroll
    for (int i = 0; i < 4; ++i) {
        u4 a = (q & 1) ? xn[i] : xc[i];      // first 16 floats of the half
        u4 b = (q & 1) ? xc[i] : xn[i];      // second 16 floats
        xh[2 * i]     = h2{(_Float16)__uint_as_float(a.x), (_Float16)__uint_as_float(a.y)};
        xh[2 * i + 1] = h2{(_Float16)__uint_as_float(a.z), (_Float16)__uint_as_float(a.w)};
        xh[8 + 2 * i]     = h2{(_Float16)__uint_as_float(b.x), (_Float16)__uint_as_float(b.y)};
        xh[8 + 2 * i + 1] = h2{(_Float16)__uint_as_float(b.z), (_Float16)__uint_as_float(b.w)};
    }

    float acc[ODIM];
#pragma unroll
    for (int o = 0; o < ODIM; ++o) acc[o] = 0.0f;

#pragma unroll
    for (int g = 0; g < 4; ++g) {          // 4 groups x 8 halfs (16B)
#pragma unroll
        for (int o = 0; o < ODIM; ++o) {
            const h2* wp = (const h2*)&Wh[h * ODIM + o][ch * 32 + g * 8];  // ds_read_b128
            acc[o] = __builtin_amdgcn_fdot2(xh[4 * g + 0], wp[0], acc[o], false);
            acc[o] = __builtin_amdgcn_fdot2(xh[4 * g + 1], wp[1], acc[o], false);
            acc[o] = __builtin_amdgcn_fdot2(xh[4 * g + 2], wp[2], acc[o], false);
            acc[o] = __builtin_amdgcn_fdot2(xh[4 * g + 3], wp[3], acc[o], false);
        }
    }

    // combine channel halves (partner = xor lane bit 1)
#pragma unroll
    for (int o = 0; o < ODIM; ++o)
        acc[o] += __shfl_xor(acc[o], 2);

    if (ch == 0) {
        int t = node_types[n];
        u32 u[ODIM];
#pragma unroll
        for (int o = 0; o < ODIM; ++o) {
            float v = acc[o] + ntab[h][o][t];
            int qi = (int)rintf(fmaf(v, 256.0f, 2048.0f));   // (v+8)*256
            qi = qi < 0 ? 0 : (qi > 4095 ? 4095 : qi);
            u[o] = (u32)qi;
        }
        u4 w;
        w.x = u[0] | (u[1] << 12) | (u[2] << 24);
        w.y = (u[2] >> 8) | (u[3] << 4) | (u[4] << 16) | (u[5] << 28);
        w.z = (u[5] >> 4) | (u[6] << 8) | (u[7] << 20);
        w.w = u[8];
        (h ? dp : sp)[n] = w;                // one 16B aligned store
    }
}

// ---- edge kernel: 1 edge/thread, sc0 gathers, LDS-staged dense NT stores ----
// (byte-identical to R13 — isolates the node change)
__global__ __launch_bounds__(256) void edge_kernel(
    const int* __restrict__ ei, const int* __restrict__ etypes,
    const u4* __restrict__ sp, const u4* __restrict__ dp,
    const float* __restrict__ W, float* __restrict__ out,
    int E)
{
    __shared__ float etab2[12][ODIM];    // etab2[t][o] = W[o][136+t] - 16 (folds dequant offsets)
    __shared__ alignas(16) float sm[256 * ODIM];   // 9216 B staging

    for (int i = threadIdx.x; i < 12 * ODIM; i += 256) {
        int t = i / ODIM, o = i - t * ODIM;
        etab2[t][o] = W[o * IN_DIM + 136 + t] - 16.0f;
    }
    __syncthreads();

    int base = blockIdx.x * 256;
    int e = base + threadIdx.x;
    int cnt = E - base; if (cnt > 256) cnt = 256;

    if (threadIdx.x < cnt) {
        // streaming index loads: non-temporal, don't evict the L2-resident proj set
        int s  = __builtin_nontemporal_load(ei + e);
        int d  = __builtin_nontemporal_load(ei + (size_t)E + e);
        int et = __builtin_nontemporal_load(etypes + e);

        // 2 random 16B gathers, L1-bypassed (sc0)
        u4 sw, dw;
        gather2_sc0(sp + s, dp + d, sw, dw);

        int us[ODIM], ud[ODIM];
        decode9(sw, us);
        decode9(dw, ud);

        const float* eb = &etab2[et][0];
#pragma unroll
        for (int o = 0; o < ODIM; ++o) {
            float v = fmaf((float)(us[o] + ud[o]), 1.0f / 256.0f, eb[o]);
            sm[threadIdx.x * ODIM + o] = tanh_fast(v);
        }
    }
    __syncthreads();

    // fully line-dense output: each nt store instruction = 64 lanes x 16B
    // contiguous = 16 whole 64B lines -> streams to HBM, zero L2 pollution,
    // zero partial-line RFO (R6/R9 lesson).
    float* ob = out + (size_t)base * ODIM;   // 9216B-aligned
    if (cnt == 256) {
        const f4* smv = (const f4*)sm;
        f4* obv = (f4*)ob;
#pragma unroll
        for (int j = threadIdx.x; j < 256 * ODIM / 4; j += 256)
            __builtin_nontemporal_store(smv[j], obv + j);
    } else {
        int tot = cnt * ODIM;
        for (int j = threadIdx.x; j < tot; j += 256)
            __builtin_nontemporal_store(sm[j], ob + j);
    }
}

extern "C" void kernel_launch(void* const* d_in, const int* in_sizes, int n_in,
                              void* d_out, int out_size, void* d_ws, size_t ws_size,
                              hipStream_t stream) {
    const float* x      = (const float*)d_in[0];
    const int*   ei     = (const int*)d_in[1];
    const int*   etypes = (const int*)d_in[2];
    const int*   ntypes = (const int*)d_in[3];
    const float* W      = (const float*)d_in[4];
    float* out = (float*)d_out;

    int N = in_sizes[0] / C;    // 100000
    int E = in_sizes[2];        // 1600000

    u4* sp = (u4*)d_ws;                  // N x 16B
    u4* dp = sp + N;                     // N x 16B  (total 3.2 MB)

    int nthreads = N * 4;
    int nblocks  = (nthreads + 255) / 256;
    node_proj_kernel<<<nblocks, 256, 0, stream>>>(x, ntypes, W, sp, dp, N);

    int eblocks = (E + 255) / 256;
    edge_kernel<<<eblocks, 256, 0, stream>>>(ei, etypes, sp, dp, W, out, E);
}